// Round 4
// baseline (414.880 us; speedup 1.0000x reference)
//
#include <hip/hip_runtime.h>
#include <math.h>

#define B 4
#define C 64
#define L 4096
#define OUTC 64
#define SCALE 10.0f
#define THRESH 1e-3f

typedef float v4f __attribute__((ext_vector_type(4)));
typedef short bf16x8 __attribute__((ext_vector_type(8)));
typedef unsigned short us8 __attribute__((ext_vector_type(8)));
typedef _Float16 f16x2 __attribute__((ext_vector_type(2)));

__device__ __forceinline__ unsigned short f2bf(float x) {
    unsigned int u = __float_as_uint(x);
    u += 0x7fffu + ((u >> 16) & 1u);          // round-to-nearest-even
    return (unsigned short)(u >> 16);
}
__device__ __forceinline__ float bf2f(unsigned short h) {
    return __uint_as_float(((unsigned int)h) << 16);
}
__device__ __forceinline__ v4f mfma16(bf16x8 a, bf16x8 b, v4f c) {
    return __builtin_amdgcn_mfma_f32_16x16x32_bf16(a, b, c, 0, 0, 0);
}
__device__ __forceinline__ unsigned pack_f16x2(float a, float b) {
    f16x2 h;
    h.x = (_Float16)a;                        // RTN converts
    h.y = (_Float16)b;
    return __builtin_bit_cast(unsigned, h);
}

// ---------------------------------------------------------------------------
// FRAGMENT-TILED operand layout (ushort units):
//   T(b,tile,chunk,lane,j) = ((b*256 + tile)*2 + chunk)*512 + lane*8 + j
// tile = col/16, chunk = c/32, lane = ((c&31)>>3)*16 + (col&15), j = c&7.
// Fragment load = base + lane*16B -> one contiguous 1 KB wave transaction.
//
// R3 CHANGE — FULL REPLAY WITH f16-PACKED e AT 2 BLOCKS/CU:
// Cross-round model: time tracks K-fragment read volume + where it's served
// (R0 1.07GB=148us ctrl, R1 1.07GB@1blk/CU=169, R2 1.61GB=165). The ideal
// structure is R1's single-compute (K read once, no pass-2 MFMA/loads); it
// lost only because e[32][4] f32 = 128 VGPR forced 1 block/CU. Fix: pack e
// as f16 pairs -> 64 VGPRs -> __launch_bounds__(512,4) holds 2 blocks/CU.
// Precision: row sums stay f32 (packing is replay-only); output-relevant
// e in [4e-4,6e-3] is f16-normal (rel err <=5e-4 -> <=~7e-6 on w); values
// flushed at f16 have w<<THRESH and are zeroed anyway.
// XCD remap (batch b -> XCDs {2b,2b+1}) + NT output stores kept from R0.
// ---------------------------------------------------------------------------

// ---------------------------------------------------------------------------
// Projection: p = l2norm(W2 @ leaky(W1 @ x)) per column, emitted as bf16
// hi/lo planes directly in the fragment-tiled layout above.
// 512 blocks x 256 threads; block->(which,b,ltile) decode is XCD-pinned.
// ---------------------------------------------------------------------------
__global__ void __launch_bounds__(256) proj_kernel(
    const float* __restrict__ q_in, const float* __restrict__ k_in,
    const float* __restrict__ W1, const float* __restrict__ W2,
    unsigned short* __restrict__ Qh, unsigned short* __restrict__ Ql,
    unsigned short* __restrict__ Kh, unsigned short* __restrict__ Kl)
{
    int bid   = blockIdx.x;        // 0..511
    int xcd   = bid & 7;
    int b     = xcd >> 1;
    int which = (bid >> 3) & 1;    // 0 = query, 1 = key
    int lt    = ((bid >> 4) << 1) | (xcd & 1);   // 0..63
    int l0    = lt << 6;
    int t     = threadIdx.x;
    int g     = t >> 6;            // 0..3  (owns channels [g*16, g*16+16))
    int l     = t & 63;

    const float* __restrict__ src =
        (which ? k_in : q_in) + (size_t)b * C * L + l0 + l;
    unsigned short* __restrict__ dh = which ? Kh : Qh;
    unsigned short* __restrict__ dl = which ? Kl : Ql;

    __shared__ float Ht[128][65];   // [h][l], pad 65 -> conflict-free
    __shared__ float red[4][64];

    float xr[C];
    #pragma unroll
    for (int c = 0; c < C; ++c)
        xr[c] = src[(size_t)c * L];

    // Stage 1: H[o][l] for o in [g*32, g*32+32)
    #pragma unroll 1
    for (int oo = 0; oo < 32; oo += 4) {
        #pragma unroll
        for (int u = 0; u < 4; ++u) {
            int o = g * 32 + oo + u;
            float h0 = 0.f, h1 = 0.f, h2 = 0.f, h3 = 0.f;
            #pragma unroll
            for (int c = 0; c < C; c += 4) {
                h0 = fmaf(W1[o * C + c + 0], xr[c + 0], h0);
                h1 = fmaf(W1[o * C + c + 1], xr[c + 1], h1);
                h2 = fmaf(W1[o * C + c + 2], xr[c + 2], h2);
                h3 = fmaf(W1[o * C + c + 3], xr[c + 3], h3);
            }
            float h = (h0 + h1) + (h2 + h3);
            Ht[o][l] = (h >= 0.0f) ? h : 0.01f * h;   // LeakyReLU(0.01)
        }
    }
    __syncthreads();

    // Stage 2: Y[o][l] for o in [g*16, g*16+16)
    float y[16];
    #pragma unroll
    for (int u = 0; u < 16; ++u) y[u] = 0.f;

    #pragma unroll 1
    for (int hh = 0; hh < 2 * C; hh += 16) {
        float hr[16];
        #pragma unroll
        for (int r = 0; r < 16; ++r)
            hr[r] = Ht[hh + r][l];
        #pragma unroll
        for (int u = 0; u < 16; ++u) {
            int o = g * 16 + u;
            #pragma unroll
            for (int h = 0; h < 16; ++h)
                y[u] = fmaf(W2[o * (2 * C) + hh + h], hr[h], y[u]);
        }
    }

    // l2norm over all 64 output channels (cross-group via LDS)
    float ss = 0.f;
    #pragma unroll
    for (int u = 0; u < 16; ++u) ss = fmaf(y[u], y[u], ss);
    red[g][l] = ss;
    __syncthreads();
    float tot = red[0][l] + red[1][l] + red[2][l] + red[3][l];
    float inv = 1.0f / fmaxf(sqrtf(tot), 1e-12f);

    // Emit bf16 hi/lo split in fragment-tiled layout.
    unsigned short hs[16], ls[16];
    #pragma unroll
    for (int u = 0; u < 16; ++u) {
        float val = y[u] * inv;
        hs[u] = f2bf(val);
        ls[u] = f2bf(val - bf2f(hs[u]));
    }
    {
        int col   = l0 + l;
        int tile  = col >> 4;
        int lnn   = col & 15;
        int chunk = g >> 1;
        int quad0 = (g & 1) * 2;
        size_t base0 = (((size_t)b * 256 + tile) * 2 + chunk) * 512
                     + (size_t)(quad0 * 16 + lnn) * 8;
        size_t base1 = base0 + 128;   // quad0+1 -> lane+16 -> +128 ushorts
        *(us8*)(dh + base0) = *(us8*)&hs[0];
        *(us8*)(dh + base1) = *(us8*)&hs[8];
        *(us8*)(dl + base0) = *(us8*)&ls[0];
        *(us8*)(dl + base1) = *(us8*)&ls[8];
    }
}

// ---------------------------------------------------------------------------
// Single-compute scores kernel, f16-packed replay. 1024 blocks (XCD-pinned
// decode) x 512 threads (8 waves); 16 q-rows per block; 2 blocks/CU via
// __launch_bounds__(512,4). Pass 1 computes exp(S-10) ONCE (f32 sums),
// packing replay values as f16 pairs (epk[32][2] = 64 VGPRs, statically
// indexed). Pass 2 is a pure register replay: no K loads, no MFMA, no exp.
// S = Qh*Kh + Qh*Kl + Ql*Kh (lo*lo dropped). |S|<=10 -> fixed shift 10.
// ---------------------------------------------------------------------------
__global__ void __launch_bounds__(512, 4) scores_kernel(
    const unsigned short* __restrict__ Qh, const unsigned short* __restrict__ Ql,
    const unsigned short* __restrict__ Kh, const unsigned short* __restrict__ Kl,
    float* __restrict__ out)
{
    int bid  = blockIdx.x;          // 0..1023
    // XCD-locality decode: batch b = (bid&7)>>1 -> one batch's K planes
    // (~1 MB) resident in each pair of XCD L2s.
    int xcd  = bid & 7;
    int b    = xcd >> 1;
    int r0   = (((bid >> 3) << 1) | (xcd & 1)) << 4;   // 16 rows, 0..4080
    int t    = threadIdx.x;
    int wave = t >> 6;
    int lane = t & 63;
    int quad = lane >> 4;
    int ln   = lane & 15;

    // A fragments (fragment-tiled): aQ[c0][hi/lo], one 16-row tile
    bf16x8 aQ[2][2];
    {
        size_t rowtile = (size_t)b * 256 + (r0 >> 4);
        #pragma unroll
        for (int c0 = 0; c0 < 2; ++c0) {
            size_t base = (rowtile * 2 + c0) * 512 + (size_t)lane * 8;
            aQ[c0][0] = *(const bf16x8*)(Qh + base);
            aQ[c0][1] = *(const bf16x8*)(Ql + base);
        }
    }

    const size_t ktb = (size_t)b * 256;
    __shared__ float wsum[16][8];
    __shared__ float rinv[16];
    __shared__ float Pt[2][16][132];   // double-buffered transpose tile

    // ---------------- pass 1: compute exp(S-10) ONCE ----------------------
    // STRIDED column assignment: iteration i covers tile ct16 = i*8 + wave,
    // i.e. global cols i*128 + wave*16 + [0,16). Store-tile i then has one
    // 16-col subtile per wave (cooperative store pattern preserved).
    // Row sums accumulate in f32; replay values packed to f16 pairs.
    unsigned epk[32][2];            // 64 VGPRs, statically indexed
    v4f ps = (v4f){0.f, 0.f, 0.f, 0.f};

    #pragma unroll
    for (int i = 0; i < 32; ++i) {
        size_t base = ((ktb + i * 8 + wave) * 2) * 512 + (size_t)lane * 8;
        bf16x8 bh0 = *(const bf16x8*)(Kh + base);
        bf16x8 bl0 = *(const bf16x8*)(Kl + base);
        bf16x8 bh1 = *(const bf16x8*)(Kh + base + 512);
        bf16x8 bl1 = *(const bf16x8*)(Kl + base + 512);

        v4f acc = (v4f){0.f, 0.f, 0.f, 0.f};
        acc = mfma16(aQ[0][0], bh0, acc);
        acc = mfma16(aQ[0][1], bh0, acc);
        acc = mfma16(aQ[0][0], bl0, acc);
        acc = mfma16(aQ[1][0], bh1, acc);
        acc = mfma16(aQ[1][1], bh1, acc);
        acc = mfma16(aQ[1][0], bl1, acc);

        float ev0 = __expf(fmaf(SCALE, acc[0], -SCALE));
        float ev1 = __expf(fmaf(SCALE, acc[1], -SCALE));
        float ev2 = __expf(fmaf(SCALE, acc[2], -SCALE));
        float ev3 = __expf(fmaf(SCALE, acc[3], -SCALE));
        ps[0] += ev0; ps[1] += ev1; ps[2] += ev2; ps[3] += ev3;
        epk[i][0] = pack_f16x2(ev0, ev1);
        epk[i][1] = pack_f16x2(ev2, ev3);
    }

    // reduce over the 16 ln-lanes (cols) per row, then across waves via LDS
    #pragma unroll
    for (int r = 0; r < 4; ++r) {
        float s = ps[r];
        s += __shfl_xor(s, 1);
        s += __shfl_xor(s, 2);
        s += __shfl_xor(s, 4);
        s += __shfl_xor(s, 8);
        if (ln == 0) wsum[quad * 4 + r][wave] = s;
    }
    __syncthreads();
    if (t < 16) {
        float s = 0.f;
        #pragma unroll
        for (int w = 0; w < 8; ++w) s += wsum[t][w];
        rinv[t] = 1.0f / s;
    }
    __syncthreads();

    float rv[4];
    #pragma unroll
    for (int r = 0; r < 4; ++r)
        rv[r] = rinv[quad * 4 + r];

    // ---------------- pass 2: f16 register replay, threshold, store -------
    float* __restrict__ outb = out + ((size_t)b * L + r0) * L;
    int srow = t >> 5;            // 0..15 (store row)
    int scol = (t & 31) * 4;      // 0..124 (16 B-aligned col)

    #pragma unroll
    for (int T = 0; T < 32; ++T) {
        int buf = T & 1;
        #pragma unroll
        for (int p = 0; p < 2; ++p) {
            f16x2 h = __builtin_bit_cast(f16x2, epk[T][p]);
            float w0 = (float)h.x * rv[2 * p + 0];
            float w1 = (float)h.y * rv[2 * p + 1];
            w0 = (w0 > THRESH) ? w0 : 0.f;
            w1 = (w1 > THRESH) ? w1 : 0.f;
            // C/D layout: col = ln, row = quad*4 + r (m89/m91)
            Pt[buf][quad * 4 + 2 * p + 0][wave * 16 + ln] = w0;
            Pt[buf][quad * 4 + 2 * p + 1][wave * 16 + ln] = w1;
        }
        __syncthreads();

        // line-complete cooperative store: 512 lanes x 16 B contiguous,
        // non-temporal so the store stream doesn't evict resident K planes.
        v4f o = *(const v4f*)&Pt[buf][srow][scol];
        __builtin_nontemporal_store(
            o, (v4f*)(outb + (size_t)srow * L + T * 128 + scol));
    }
}

// ---------------------------------------------------------------------------
extern "C" void kernel_launch(void* const* d_in, const int* in_sizes, int n_in,
                              void* d_out, int out_size, void* d_ws, size_t ws_size,
                              hipStream_t stream) {
    const float* query = (const float*)d_in[0];
    const float* key   = (const float*)d_in[1];
    const float* W1    = (const float*)d_in[2];
    const float* W2    = (const float*)d_in[3];
    float* out = (float*)d_out;

    // ws layout (ushorts): Qh | Ql | Kh | Kl, each B*L*OUTC = 1048576 elems
    unsigned short* Qh = (unsigned short*)d_ws;
    unsigned short* Ql = Qh + (size_t)B * L * OUTC;
    unsigned short* Kh = Ql + (size_t)B * L * OUTC;
    unsigned short* Kl = Kh + (size_t)B * L * OUTC;

    hipLaunchKernelGGL(proj_kernel, dim3(512), dim3(256), 0, stream,
                       query, key, W1, W2, Qh, Ql, Kh, Kl);
    hipLaunchKernelGGL(scores_kernel, dim3(1024), dim3(512), 0, stream,
                       Qh, Ql, Kh, Kl, out);
}

// Round 5
// 364.157 us; speedup vs baseline: 1.1393x; 1.1393x over previous
//
#include <hip/hip_runtime.h>
#include <math.h>

#define B 4
#define C 64
#define L 4096
#define OUTC 64
#define SCALE 10.0f
#define THRESH 1e-3f

typedef float v4f __attribute__((ext_vector_type(4)));
typedef short bf16x8 __attribute__((ext_vector_type(8)));
typedef unsigned short us8 __attribute__((ext_vector_type(8)));

__device__ __forceinline__ unsigned short f2bf(float x) {
    unsigned int u = __float_as_uint(x);
    u += 0x7fffu + ((u >> 16) & 1u);          // round-to-nearest-even
    return (unsigned short)(u >> 16);
}
__device__ __forceinline__ float bf2f(unsigned short h) {
    return __uint_as_float(((unsigned int)h) << 16);
}
__device__ __forceinline__ v4f mfma16(bf16x8 a, bf16x8 b, v4f c) {
    return __builtin_amdgcn_mfma_f32_16x16x32_bf16(a, b, c, 0, 0, 0);
}

// ---------------------------------------------------------------------------
// FRAGMENT-TILED operand layout (ushort units):
//   T(b,tile,chunk,lane,j) = ((b*256 + tile)*2 + chunk)*512 + lane*8 + j
// tile = col/16, chunk = c/32, lane = ((c&31)>>3)*16 + (col&15), j = c&7.
// Fragment load = base + lane*16B -> one contiguous 1 KB wave transaction.
//
// R4 CHANGE — R0's EXACT MATH, LATENCY-PIPELINED:
// R3's counters (first direct scores profile): VGPR_Count=64 + 142MB excess
// WRITE + 111MB FETCH = launch_bounds(512,4) clamped VGPRs and SPILLED the
// replay array to scratch; MfmaUtil 5%, VALU 11%, HBM 36% -> latency-bound,
// all pipes idle. Replay line abandoned (R1 occupancy / R2,R3 spill).
// This round: R0's 2-pass recompute structure (best measured), with the
// exposed latency removed:
//   1. pass 1: A/B register double-buffer — load tile ct+1/ct+2 while
//      computing ct (was `#pragma unroll 1` serial load->wait->MFMA).
//   2. pass 2: prefetch next tile's K fragments BEFORE the barrier, and
//      use lgkmcnt(0)-only + raw s_barrier (NOT __syncthreads, which
//      drains vmcnt(0)) so prefetched loads stay in flight across the
//      barrier (m201-verified plain-HIP pattern; sched_barrier(0) fences).
//   3. __launch_bounds__(512) only — no min-waves clause (the spill trap).
// Per-wave accumulation order unchanged -> bit-identical to R0:
// absmax must be exactly 0.0009994507.
// XCD remap (batch b -> XCDs {2b,2b+1}) + NT output stores kept from R0.
// ---------------------------------------------------------------------------

// ---------------------------------------------------------------------------
// Projection: p = l2norm(W2 @ leaky(W1 @ x)) per column, emitted as bf16
// hi/lo planes directly in the fragment-tiled layout above.
// 512 blocks x 256 threads; block->(which,b,ltile) decode is XCD-pinned.
// ---------------------------------------------------------------------------
__global__ void __launch_bounds__(256) proj_kernel(
    const float* __restrict__ q_in, const float* __restrict__ k_in,
    const float* __restrict__ W1, const float* __restrict__ W2,
    unsigned short* __restrict__ Qh, unsigned short* __restrict__ Ql,
    unsigned short* __restrict__ Kh, unsigned short* __restrict__ Kl)
{
    int bid   = blockIdx.x;        // 0..511
    int xcd   = bid & 7;
    int b     = xcd >> 1;
    int which = (bid >> 3) & 1;    // 0 = query, 1 = key
    int lt    = ((bid >> 4) << 1) | (xcd & 1);   // 0..63
    int l0    = lt << 6;
    int t     = threadIdx.x;
    int g     = t >> 6;            // 0..3  (owns channels [g*16, g*16+16))
    int l     = t & 63;

    const float* __restrict__ src =
        (which ? k_in : q_in) + (size_t)b * C * L + l0 + l;
    unsigned short* __restrict__ dh = which ? Kh : Qh;
    unsigned short* __restrict__ dl = which ? Kl : Ql;

    __shared__ float Ht[128][65];   // [h][l], pad 65 -> conflict-free
    __shared__ float red[4][64];

    float xr[C];
    #pragma unroll
    for (int c = 0; c < C; ++c)
        xr[c] = src[(size_t)c * L];

    // Stage 1: H[o][l] for o in [g*32, g*32+32)
    #pragma unroll 1
    for (int oo = 0; oo < 32; oo += 4) {
        #pragma unroll
        for (int u = 0; u < 4; ++u) {
            int o = g * 32 + oo + u;
            float h0 = 0.f, h1 = 0.f, h2 = 0.f, h3 = 0.f;
            #pragma unroll
            for (int c = 0; c < C; c += 4) {
                h0 = fmaf(W1[o * C + c + 0], xr[c + 0], h0);
                h1 = fmaf(W1[o * C + c + 1], xr[c + 1], h1);
                h2 = fmaf(W1[o * C + c + 2], xr[c + 2], h2);
                h3 = fmaf(W1[o * C + c + 3], xr[c + 3], h3);
            }
            float h = (h0 + h1) + (h2 + h3);
            Ht[o][l] = (h >= 0.0f) ? h : 0.01f * h;   // LeakyReLU(0.01)
        }
    }
    __syncthreads();

    // Stage 2: Y[o][l] for o in [g*16, g*16+16)
    float y[16];
    #pragma unroll
    for (int u = 0; u < 16; ++u) y[u] = 0.f;

    #pragma unroll 1
    for (int hh = 0; hh < 2 * C; hh += 16) {
        float hr[16];
        #pragma unroll
        for (int r = 0; r < 16; ++r)
            hr[r] = Ht[hh + r][l];
        #pragma unroll
        for (int u = 0; u < 16; ++u) {
            int o = g * 16 + u;
            #pragma unroll
            for (int h = 0; h < 16; ++h)
                y[u] = fmaf(W2[o * (2 * C) + hh + h], hr[h], y[u]);
        }
    }

    // l2norm over all 64 output channels (cross-group via LDS)
    float ss = 0.f;
    #pragma unroll
    for (int u = 0; u < 16; ++u) ss = fmaf(y[u], y[u], ss);
    red[g][l] = ss;
    __syncthreads();
    float tot = red[0][l] + red[1][l] + red[2][l] + red[3][l];
    float inv = 1.0f / fmaxf(sqrtf(tot), 1e-12f);

    // Emit bf16 hi/lo split in fragment-tiled layout.
    unsigned short hs[16], ls[16];
    #pragma unroll
    for (int u = 0; u < 16; ++u) {
        float val = y[u] * inv;
        hs[u] = f2bf(val);
        ls[u] = f2bf(val - bf2f(hs[u]));
    }
    {
        int col   = l0 + l;
        int tile  = col >> 4;
        int lnn   = col & 15;
        int chunk = g >> 1;
        int quad0 = (g & 1) * 2;
        size_t base0 = (((size_t)b * 256 + tile) * 2 + chunk) * 512
                     + (size_t)(quad0 * 16 + lnn) * 8;
        size_t base1 = base0 + 128;   // quad0+1 -> lane+16 -> +128 ushorts
        *(us8*)(dh + base0) = *(us8*)&hs[0];
        *(us8*)(dh + base1) = *(us8*)&hs[8];
        *(us8*)(dl + base0) = *(us8*)&ls[0];
        *(us8*)(dl + base1) = *(us8*)&ls[8];
    }
}

// Load the 4 K-plane fragments of absolute column-tile TILE into set SET.
#define LOADK(SET, TILE) do {                                            \
    size_t _kb = ((ktb + (size_t)(TILE)) * 2) * 512 + (size_t)lane * 8;  \
    SET##h0 = *(const bf16x8*)(Kh + _kb);                                \
    SET##l0 = *(const bf16x8*)(Kl + _kb);                                \
    SET##h1 = *(const bf16x8*)(Kh + _kb + 512);                          \
    SET##l1 = *(const bf16x8*)(Kl + _kb + 512);                          \
} while (0)

// ---------------------------------------------------------------------------
// Scores kernel: R0 structure (2-pass recompute, 32 rows/block), pipelined.
// 512 blocks (XCD-pinned decode) x 512 threads (8 waves).
// S = Qh*Kh + Qh*Kl + Ql*Kh (lo*lo dropped). |S|<=10 -> fixed shift 10.
// ---------------------------------------------------------------------------
__global__ void __launch_bounds__(512) scores_kernel(
    const unsigned short* __restrict__ Qh, const unsigned short* __restrict__ Ql,
    const unsigned short* __restrict__ Kh, const unsigned short* __restrict__ Kl,
    float* __restrict__ out)
{
    int bid  = blockIdx.x;          // 0..511
    int xcd  = bid & 7;
    int b    = xcd >> 1;
    int r0   = (((bid >> 3) << 1) | (xcd & 1)) << 5;   // 32 rows
    int t    = threadIdx.x;
    int wave = t >> 6;
    int lane = t & 63;
    int quad = lane >> 4;
    int ln   = lane & 15;

    // A fragments (fragment-tiled): aQ[rt][c0][hi/lo]
    bf16x8 aQ[2][2][2];
    {
        #pragma unroll
        for (int rt = 0; rt < 2; ++rt) {
            size_t rowtile = (size_t)b * 256 + (r0 >> 4) + rt;
            #pragma unroll
            for (int c0 = 0; c0 < 2; ++c0) {
                size_t base = (rowtile * 2 + c0) * 512 + (size_t)lane * 8;
                aQ[rt][c0][0] = *(const bf16x8*)(Qh + base);
                aQ[rt][c0][1] = *(const bf16x8*)(Ql + base);
            }
        }
    }

    const size_t ktb = (size_t)b * 256;
    __shared__ float wsum[32][8];
    __shared__ float rinv[32];
    __shared__ float Pt[2][32][132];   // double-buffered transpose tile

    // ---------------- pass 1: row sums of exp(S - 10), pipelined ----------
    v4f ps[2];
    ps[0] = (v4f){0.f, 0.f, 0.f, 0.f};
    ps[1] = (v4f){0.f, 0.f, 0.f, 0.f};

    bf16x8 Ah0, Al0, Ah1, Al1, Bh0, Bl0, Bh1, Bl1;
    LOADK(A, wave * 32 + 0);

#define P1TILE(SET) do {                                                 \
    _Pragma("unroll")                                                    \
    for (int rt = 0; rt < 2; ++rt) {                                     \
        v4f acc = (v4f){0.f, 0.f, 0.f, 0.f};                             \
        acc = mfma16(aQ[rt][0][0], SET##h0, acc);                        \
        acc = mfma16(aQ[rt][0][1], SET##h0, acc);                        \
        acc = mfma16(aQ[rt][0][0], SET##l0, acc);                        \
        acc = mfma16(aQ[rt][1][0], SET##h1, acc);                        \
        acc = mfma16(aQ[rt][1][1], SET##h1, acc);                        \
        acc = mfma16(aQ[rt][1][0], SET##l1, acc);                        \
        _Pragma("unroll")                                                \
        for (int r = 0; r < 4; ++r)                                      \
            ps[rt][r] += __expf(fmaf(SCALE, acc[r], -SCALE));            \
    }                                                                    \
} while (0)

    #pragma unroll 1
    for (int ct = 0; ct < 32; ct += 2) {
        LOADK(B, wave * 32 + ct + 1);   // prefetch odd tile
        P1TILE(A);                       // compute even tile
        if (ct + 2 < 32)
            LOADK(A, wave * 32 + ct + 2); // prefetch next even tile
        P1TILE(B);                       // compute odd tile
    }

    // reduce over the 16 ln-lanes (cols) per row, then across waves via LDS
    #pragma unroll
    for (int rt = 0; rt < 2; ++rt) {
        #pragma unroll
        for (int r = 0; r < 4; ++r) {
            float s = ps[rt][r];
            s += __shfl_xor(s, 1);
            s += __shfl_xor(s, 2);
            s += __shfl_xor(s, 4);
            s += __shfl_xor(s, 8);
            if (ln == 0) wsum[rt * 16 + quad * 4 + r][wave] = s;
        }
    }
    __syncthreads();
    if (t < 32) {
        float s = 0.f;
        #pragma unroll
        for (int w = 0; w < 8; ++w) s += wsum[t][w];
        rinv[t] = 1.0f / s;
    }
    __syncthreads();

    float rv[2][4];
    #pragma unroll
    for (int rt = 0; rt < 2; ++rt)
        #pragma unroll
        for (int r = 0; r < 4; ++r)
            rv[rt][r] = rinv[rt * 16 + quad * 4 + r];

    // ---------------- pass 2: recompute, normalize, threshold, store ------
    // Pipelined: tile T+1's K fragments are loaded BEFORE tile T's barrier;
    // the barrier is lgkmcnt(0)-only + raw s_barrier, so those global loads
    // remain in flight across it (vmcnt never drained in the loop).
    float* __restrict__ outb = out + ((size_t)b * L + r0) * L;
    int srow = t >> 5;            // 0..15 (store row within half-tile)
    int scol = (t & 31) * 4;      // 0..124 (16 B-aligned col)

#define P2TILE(SET, TT, BUF) do {                                        \
    _Pragma("unroll")                                                    \
    for (int rt = 0; rt < 2; ++rt) {                                     \
        v4f acc = (v4f){0.f, 0.f, 0.f, 0.f};                             \
        acc = mfma16(aQ[rt][0][0], SET##h0, acc);                        \
        acc = mfma16(aQ[rt][0][1], SET##h0, acc);                        \
        acc = mfma16(aQ[rt][0][0], SET##l0, acc);                        \
        acc = mfma16(aQ[rt][1][0], SET##h1, acc);                        \
        acc = mfma16(aQ[rt][1][1], SET##h1, acc);                        \
        acc = mfma16(aQ[rt][1][0], SET##l1, acc);                        \
        _Pragma("unroll")                                                \
        for (int r = 0; r < 4; ++r) {                                    \
            float w = __expf(fmaf(SCALE, acc[r], -SCALE)) * rv[rt][r];   \
            w = (w > THRESH) ? w : 0.f;                                  \
            Pt[BUF][rt * 16 + quad * 4 + r][wave * 16 + ln] = w;         \
        }                                                                \
    }                                                                    \
    __builtin_amdgcn_sched_barrier(0);                                   \
    asm volatile("s_waitcnt lgkmcnt(0)" ::: "memory");                   \
    __builtin_amdgcn_s_barrier();                                        \
    __builtin_amdgcn_sched_barrier(0);                                   \
    _Pragma("unroll")                                                    \
    for (int j = 0; j < 2; ++j) {                                        \
        int row = j * 16 + srow;                                         \
        v4f o = *(const v4f*)&Pt[BUF][row][scol];                        \
        __builtin_nontemporal_store(                                     \
            o, (v4f*)(outb + (size_t)row * L + (TT) * 128 + scol));      \
    }                                                                    \
} while (0)

    LOADK(A, 0 * 8 + wave);              // prologue: tile 0 fragments

    #pragma unroll 1
    for (int T = 0; T < 32; T += 2) {
        LOADK(B, (T + 1) * 8 + wave);    // prefetch odd tile
        if (T + 2 < 32) {
            P2TILE(A, T, 0);             // compute/store even tile
            LOADK(A, (T + 2) * 8 + wave);// prefetch next even tile
        } else {
            P2TILE(A, T, 0);
        }
        P2TILE(B, T + 1, 1);             // compute/store odd tile
    }
}

// ---------------------------------------------------------------------------
extern "C" void kernel_launch(void* const* d_in, const int* in_sizes, int n_in,
                              void* d_out, int out_size, void* d_ws, size_t ws_size,
                              hipStream_t stream) {
    const float* query = (const float*)d_in[0];
    const float* key   = (const float*)d_in[1];
    const float* W1    = (const float*)d_in[2];
    const float* W2    = (const float*)d_in[3];
    float* out = (float*)d_out;

    // ws layout (ushorts): Qh | Ql | Kh | Kl, each B*L*OUTC = 1048576 elems
    unsigned short* Qh = (unsigned short*)d_ws;
    unsigned short* Ql = Qh + (size_t)B * L * OUTC;
    unsigned short* Kh = Ql + (size_t)B * L * OUTC;
    unsigned short* Kl = Kh + (size_t)B * L * OUTC;

    hipLaunchKernelGGL(proj_kernel, dim3(512), dim3(256), 0, stream,
                       query, key, W1, W2, Qh, Ql, Kh, Kl);
    hipLaunchKernelGGL(scores_kernel, dim3(512), dim3(512), 0, stream,
                       Qh, Ql, Kh, Kl, out);
}